// Round 8
// baseline (644.938 us; speedup 1.0000x reference)
//
#include <hip/hip_runtime.h>
#include <hip/hip_bf16.h>
#include <math.h>

typedef __attribute__((ext_vector_type(8))) short short8;
typedef __attribute__((ext_vector_type(4))) float f32x4;
typedef __attribute__((ext_vector_type(4))) int i32x4;

__device__ inline ushort f2bf(float f) {
    uint u = __builtin_bit_cast(uint, f);
    u += 0x7fffu + ((u >> 16) & 1u);          // round-to-nearest-even
    return (ushort)(u >> 16);
}
__device__ inline float bf2f(ushort h) {
    return __builtin_bit_cast(float, (uint)h << 16);
}

// ---------------- degree / CSR build ----------------

__global__ __launch_bounds__(256) void count_kernel(const int* __restrict__ dst, int* __restrict__ cnt, int E) {
    int t = blockIdx.x * blockDim.x + threadIdx.x;
    int stride = gridDim.x * blockDim.x;
    int E4 = E >> 2;
    const i32x4* d4 = (const i32x4*)dst;
    for (int e = t; e < E4; e += stride) {
        i32x4 v = d4[e];
        atomicAdd(&cnt[v.x], 1);
        atomicAdd(&cnt[v.y], 1);
        atomicAdd(&cnt[v.z], 1);
        atomicAdd(&cnt[v.w], 1);
    }
    for (int e = E4 * 4 + t; e < E; e += stride)
        atomicAdd(&cnt[dst[e]], 1);
}

__global__ __launch_bounds__(256) void dinv_kernel(const int* __restrict__ cnt, float* __restrict__ dinv, int N) {
    int i = blockIdx.x * 256 + threadIdx.x;
    if (i < N) dinv[i] = rsqrtf((float)(cnt[i] + 1));   // +1 self loop; deg >= 1 always
}

__global__ __launch_bounds__(1024) void scan_kernel(const int* __restrict__ cnt, int* __restrict__ offs, int N) {
    __shared__ int part[1024];
    int tid = threadIdx.x;
    int chunk = (((N + 1023) >> 10) + 3) & ~3;      // multiple of 4 -> aligned int4
    int beg = tid * chunk;
    int end = beg + chunk; if (end > N) end = N;
    int s = 0;
    int i = beg;
    for (; i + 3 < end; i += 4) {
        int4 v = *(const int4*)(cnt + i);
        s += v.x + v.y + v.z + v.w;
    }
    for (; i < end; ++i) s += cnt[i];
    part[tid] = s;
    __syncthreads();
    for (int off = 1; off < 1024; off <<= 1) {
        int t = (tid >= off) ? part[tid - off] : 0;
        __syncthreads();
        part[tid] += t;
        __syncthreads();
    }
    int run = (tid > 0) ? part[tid - 1] : 0;
    i = beg;
    for (; i + 3 < end; i += 4) {
        int4 v = *(const int4*)(cnt + i);
        offs[i] = run; run += v.x;
        offs[i + 1] = run; run += v.y;
        offs[i + 2] = run; run += v.z;
        offs[i + 3] = run; run += v.w;
    }
    for (; i < end; ++i) { offs[i] = run; run += cnt[i]; }
    if (beg < N && end == N) offs[N] = run;
}

// cursor8[g] = offs[lo_g] : append cursors for the 8 dst-range buckets
__global__ void init8_kernel(const int* __restrict__ offs, int* __restrict__ cursor8, int N) {
    int t = threadIdx.x;
    if (t < 8) cursor8[t] = offs[(int)(((long long)N * t) >> 3)];
}

// ---------------- bucket pass: partition edges into 8 dst-range buckets ----------------
// Bucket g's region in bsrc/bdst = [offs[lo_g], offs[hi_g]) (same partition as csr).
#define BKE 2048

__global__ __launch_bounds__(256) void bucket_kernel(const int* __restrict__ src, const int* __restrict__ dst,
                                                     int* __restrict__ cursor8,
                                                     int* __restrict__ bsrc, int* __restrict__ bdst,
                                                     int E, int N) {
    __shared__ int hist[8];
    __shared__ int base[8];
    int tid = threadIdx.x;
    int e0 = blockIdx.x * BKE;
    int e1 = e0 + BKE; if (e1 > E) e1 = E;
    if (e0 >= E) return;
    if (tid < 8) hist[tid] = 0;
    __syncthreads();
    int myd[8], mys[8], myg[8], myr[8];
    #pragma unroll
    for (int it = 0; it < 8; ++it) {
        int e = e0 + tid + it * 256;
        myg[it] = -1;
        if (e < e1) {
            int d = dst[e];
            int sv = src[e];
            int g = (int)(((long long)d * 8) / N);
            while (d <  (int)(((long long)N * g) >> 3)) --g;
            while (d >= (int)(((long long)N * (g + 1)) >> 3)) ++g;
            myd[it] = d; mys[it] = sv; myg[it] = g;
            myr[it] = atomicAdd(&hist[g], 1);
        }
    }
    __syncthreads();
    if (tid < 8) base[tid] = atomicAdd(&cursor8[tid], hist[tid]);
    __syncthreads();
    #pragma unroll
    for (int it = 0; it < 8; ++it) {
        if (myg[it] >= 0) {
            int pos = base[myg[it]] + myr[it];
            bdst[pos] = myd[it];
            bsrc[pos] = mys[it];
        }
    }
}

// ---------------- scatter pass 2: within-bucket scatter (L2-resident csr window) ----------------

__global__ __launch_bounds__(256) void scatter2_kernel(const int* __restrict__ bsrc, const int* __restrict__ bdst,
                                                       const int* __restrict__ offs, int* __restrict__ cursor,
                                                       int* __restrict__ csr, int N) {
    int grp = blockIdx.x & 7;
    int lo = (int)(((long long)N * grp) >> 3);
    int hi = (int)(((long long)N * (grp + 1)) >> 3);
    int eb = offs[lo], ee = offs[hi];
    int nb = gridDim.x >> 3;
    int gb = blockIdx.x >> 3;
    for (int e = eb + gb * 256 + threadIdx.x; e < ee; e += nb * 256) {
        int d = bdst[e];
        int p = atomicAdd(&cursor[d], 1);
        csr[offs[d] + p] = bsrc[e];
    }
}

// ---------------- weight prep: Wt[128][512] bf16 (transposed), bcat[128], W3s[32*40], b3s[40] ----

__global__ __launch_bounds__(256) void prep_kernel(const float* __restrict__ W1a, const float* __restrict__ W1b,
                                                   const float* __restrict__ W2a, const float* __restrict__ W2b,
                                                   const float* __restrict__ b1a, const float* __restrict__ b1b,
                                                   const float* __restrict__ b2a, const float* __restrict__ b2b,
                                                   const float* __restrict__ W3a, const float* __restrict__ W3b,
                                                   const float* __restrict__ b3a, const float* __restrict__ b3b,
                                                   ushort* __restrict__ Wt, float* __restrict__ bcat,
                                                   float* __restrict__ W3s, float* __restrict__ b3s) {
    int idx = blockIdx.x * 256 + threadIdx.x;
    if (idx < 128 * 512) {
        int c = idx >> 9, k = idx & 511;   // Wt[c][k] = Wcat[k][c]
        const float* W = (c < 32) ? W1a : (c < 64) ? W1b : (c < 96) ? W2a : W2b;
        Wt[idx] = f2bf(W[k * 32 + (c & 31)]);
    }
    if (idx < 1280) W3s[idx] = W3a[idx] + W3b[idx];
    if (idx < 128) {
        const float* b = (idx < 32) ? b1a : (idx < 64) ? b1b : (idx < 96) ? b2a : b2b;
        bcat[idx] = b[idx & 31];
    }
    if (idx < 40) b3s[idx] = b3a[idx] + b3b[idx];
}

// ---------------- MFMA GEMM: HWp[N][128] = bf16( (X@Wcat)[r][c] * dinv[r] ) ----------------

#define GBM 64

__global__ __launch_bounds__(256) void gemm_mfma(const float* __restrict__ X,
                                                 const ushort* __restrict__ Wt,
                                                 const float* __restrict__ dinv,
                                                 ushort* __restrict__ HWp, int N) {
    __shared__ ushort Alds[2][64 * 64];    // [buf][row][k] 16B chunks swz: c' = c ^ (row&7)
    __shared__ ushort Blds[2][128 * 64];
    const int tid = threadIdx.x;
    const int lane = tid & 63;
    const int wave = tid >> 6;
    const int rQ = lane & 15, g = lane >> 4;
    const int swz = rQ & 7;
    const int rowBase = blockIdx.x * GBM;

    const int ar = tid >> 2, aq = tid & 3;
    int arow = rowBase + ar; if (arow > N - 1) arow = N - 1;
    const float* aglob = X + (size_t)arow * 512 + aq * 4;

    const int br = tid >> 1, bh = tid & 1;
    const ushort* bglob = Wt + (size_t)br * 512 + bh * 32;

    float4 a4[4];
    uint4 b4[4];
    f32x4 acc[4][2] = {};

#define LOAD_REGS(k0)                                                       \
    {                                                                       \
        _Pragma("unroll")                                                   \
        for (int i = 0; i < 4; ++i) a4[i] = *(const float4*)(aglob + (k0) + i * 16); \
        _Pragma("unroll")                                                   \
        for (int i = 0; i < 4; ++i) b4[i] = *(const uint4*)(bglob + (k0) + i * 8);   \
    }

#define WRITE_LDS(buf)                                                      \
    {                                                                       \
        _Pragma("unroll")                                                   \
        for (int i = 0; i < 4; ++i) {                                       \
            int c = i * 2 + (aq >> 1);                                      \
            ushort4 u; u.x = f2bf(a4[i].x); u.y = f2bf(a4[i].y);            \
            u.z = f2bf(a4[i].z); u.w = f2bf(a4[i].w);                       \
            *(ushort4*)(&Alds[buf][ar * 64 + ((c ^ (ar & 7)) << 3) + (aq & 1) * 4]) = u; \
        }                                                                   \
        ushort* bp = &Blds[buf][br * 64];                                   \
        _Pragma("unroll")                                                   \
        for (int i = 0; i < 4; ++i) {                                       \
            int c = bh * 4 + i;                                             \
            *(uint4*)(bp + ((c ^ (br & 7)) << 3)) = b4[i];                  \
        }                                                                   \
    }

#define COMPUTE(buf)                                                        \
    {                                                                       \
        short8 bf[2][2];                                                    \
        _Pragma("unroll")                                                   \
        for (int ct2 = 0; ct2 < 2; ++ct2) {                                 \
            int brow = wave * 32 + ct2 * 16 + rQ;                           \
            _Pragma("unroll")                                               \
            for (int sub = 0; sub < 2; ++sub)                               \
                bf[ct2][sub] = *(const short8*)(&Blds[buf][brow * 64 + (((sub * 4 + g) ^ swz) << 3)]); \
        }                                                                   \
        _Pragma("unroll")                                                   \
        for (int rt = 0; rt < 4; ++rt) {                                    \
            int arw = rt * 16 + rQ;                                         \
            _Pragma("unroll")                                               \
            for (int sub = 0; sub < 2; ++sub) {                             \
                short8 af = *(const short8*)(&Alds[buf][arw * 64 + (((sub * 4 + g) ^ swz) << 3)]); \
                _Pragma("unroll")                                           \
                for (int ct2 = 0; ct2 < 2; ++ct2)                           \
                    acc[rt][ct2] = __builtin_amdgcn_mfma_f32_16x16x32_bf16( \
                        af, bf[ct2][sub], acc[rt][ct2], 0, 0, 0);           \
            }                                                               \
        }                                                                   \
    }

    LOAD_REGS(0);
    WRITE_LDS(0);
    for (int s = 0; s < 8; ++s) {
        __syncthreads();
        if (s + 1 < 8) LOAD_REGS((s + 1) * 64);
        COMPUTE(s & 1);
        if (s + 1 < 8) {
            __syncthreads();
            WRITE_LDS((s + 1) & 1);
        }
    }

    #pragma unroll
    for (int rt = 0; rt < 4; ++rt) {
        #pragma unroll
        for (int j = 0; j < 4; ++j) {
            int r = rowBase + rt * 16 + g * 4 + j;
            if (r < N) {
                float dv = dinv[r];
                #pragma unroll
                for (int ct2 = 0; ct2 < 2; ++ct2) {
                    int c = wave * 32 + ct2 * 16 + rQ;
                    HWp[(size_t)r * 128 + c] = f2bf(acc[rt][ct2][j] * dv);
                }
            }
        }
    }
#undef LOAD_REGS
#undef WRITE_LDS
#undef COMPUTE
}

// ---------------- aggregation 128 (bf16 gather, unroll-4 MLP) + fused relu/bias/block-sum ----------

__global__ __launch_bounds__(256) void agg128(const ushort* __restrict__ HWp, const float* __restrict__ dinv,
                                              const int* __restrict__ offs, const int* __restrict__ csr,
                                              const float* __restrict__ bcat, ushort* __restrict__ xsp, int N) {
    int t = blockIdx.x * 256 + threadIdx.x;
    int node = t >> 5, c = t & 31;      // lane c holds features 4c..4c+3
    if (node >= N) return;
    const ushort4* H = (const ushort4*)HWp;
    ushort4 h = H[(size_t)node * 32 + c];
    float a0 = bf2f(h.x), a1 = bf2f(h.y), a2 = bf2f(h.z), a3 = bf2f(h.w);
    int j = offs[node];
    int e1 = offs[node + 1];
    int jend = j + ((e1 - j) & ~3);
    for (; j < jend; j += 4) {
        int s0 = csr[j], s1 = csr[j + 1], s2 = csr[j + 2], s3 = csr[j + 3];
        ushort4 v0 = H[(size_t)s0 * 32 + c];
        ushort4 v1 = H[(size_t)s1 * 32 + c];
        ushort4 v2 = H[(size_t)s2 * 32 + c];
        ushort4 v3 = H[(size_t)s3 * 32 + c];
        a0 += bf2f(v0.x) + bf2f(v1.x) + bf2f(v2.x) + bf2f(v3.x);
        a1 += bf2f(v0.y) + bf2f(v1.y) + bf2f(v2.y) + bf2f(v3.y);
        a2 += bf2f(v0.z) + bf2f(v1.z) + bf2f(v2.z) + bf2f(v3.z);
        a3 += bf2f(v0.w) + bf2f(v1.w) + bf2f(v2.w) + bf2f(v3.w);
    }
    for (; j < e1; ++j) {
        int s = csr[j];
        ushort4 v = H[(size_t)s * 32 + c];
        a0 += bf2f(v.x); a1 += bf2f(v.y); a2 += bf2f(v.z); a3 += bf2f(v.w);
    }
    float di = dinv[node];
    float4 b = *(const float4*)(bcat + c * 4);
    float r0 = fmaxf(di * a0 + b.x, 0.f);
    float r1 = fmaxf(di * a1 + b.y, 0.f);
    float r2 = fmaxf(di * a2 + b.z, 0.f);
    float r3 = fmaxf(di * a3 + b.w, 0.f);
    r0 += __shfl_xor(r0, 8);  r1 += __shfl_xor(r1, 8);  r2 += __shfl_xor(r2, 8);  r3 += __shfl_xor(r3, 8);
    r0 += __shfl_xor(r0, 16); r1 += __shfl_xor(r1, 16); r2 += __shfl_xor(r2, 16); r3 += __shfl_xor(r3, 16);
    if ((c & 24) == 0) {
        ushort4 o;
        o.x = f2bf(r0 * di); o.y = f2bf(r1 * di); o.z = f2bf(r2 * di); o.w = f2bf(r3 * di);
        *(ushort4*)(xsp + (size_t)node * 32 + c * 4) = o;
    }
}

// ---------------- aggregation 32 (bf16 gather, unroll-4 MLP) -> axs f32 ----------------

__global__ __launch_bounds__(256) void agg32(const ushort* __restrict__ xsp, const float* __restrict__ dinv,
                                             const int* __restrict__ offs, const int* __restrict__ csr,
                                             float* __restrict__ axs, int N) {
    int t = blockIdx.x * 256 + threadIdx.x;
    int node = t >> 2, l = t & 3;
    if (node >= N) return;
    const short8* Xr = (const short8*)xsp;   // [N][4] chunks of 8 bf16
    short8 h = Xr[(size_t)node * 4 + l];
    float a[8];
    #pragma unroll
    for (int i = 0; i < 8; ++i) a[i] = bf2f((ushort)h[i]);
    int j = offs[node];
    int e1 = offs[node + 1];
    int jend = j + ((e1 - j) & ~3);
    for (; j < jend; j += 4) {
        int s0 = csr[j], s1 = csr[j + 1], s2 = csr[j + 2], s3 = csr[j + 3];
        short8 v0 = Xr[(size_t)s0 * 4 + l];
        short8 v1 = Xr[(size_t)s1 * 4 + l];
        short8 v2 = Xr[(size_t)s2 * 4 + l];
        short8 v3 = Xr[(size_t)s3 * 4 + l];
        #pragma unroll
        for (int i = 0; i < 8; ++i)
            a[i] += bf2f((ushort)v0[i]) + bf2f((ushort)v1[i]) + bf2f((ushort)v2[i]) + bf2f((ushort)v3[i]);
    }
    for (; j < e1; ++j) {
        int s = csr[j];
        short8 v = Xr[(size_t)s * 4 + l];
        #pragma unroll
        for (int i = 0; i < 8; ++i) a[i] += bf2f((ushort)v[i]);
    }
    float di = dinv[node];
    float4 o0 = make_float4(a[0] * di, a[1] * di, a[2] * di, a[3] * di);
    float4 o1 = make_float4(a[4] * di, a[5] * di, a[6] * di, a[7] * di);
    float* dst = axs + (size_t)node * 32 + l * 8;
    *(float4*)dst = o0;
    *(float4*)(dst + 4) = o1;
}

// ---------------- final: logits = axs @ W3s + b3s ; log_softmax ----------------

__global__ __launch_bounds__(256) void final_kernel(const float* __restrict__ axs, const float* __restrict__ W3s,
                                                    const float* __restrict__ b3s, float* __restrict__ out, int N) {
    __shared__ float w[32 * 40];
    __shared__ float b[40];
    int tid = threadIdx.x;
    for (int i = tid; i < 1280; i += 256) w[i] = W3s[i];
    if (tid < 40) b[tid] = b3s[tid];
    __syncthreads();
    int i = blockIdx.x * 256 + tid;
    if (i >= N) return;
    float a[32];
    #pragma unroll
    for (int q = 0; q < 8; ++q) {
        float4 v = *(const float4*)(axs + (size_t)i * 32 + q * 4);
        a[q * 4] = v.x; a[q * 4 + 1] = v.y; a[q * 4 + 2] = v.z; a[q * 4 + 3] = v.w;
    }
    float acc[40];
    #pragma unroll
    for (int c = 0; c < 40; ++c) acc[c] = b[c];
    #pragma unroll
    for (int k = 0; k < 32; ++k) {
        float av = a[k];
        #pragma unroll
        for (int c = 0; c < 40; ++c) acc[c] += av * w[k * 40 + c];
    }
    float m = acc[0];
    #pragma unroll
    for (int c = 1; c < 40; ++c) m = fmaxf(m, acc[c]);
    float sum = 0.f;
    #pragma unroll
    for (int c = 0; c < 40; ++c) sum += expf(acc[c] - m);
    float lg = m + logf(sum);
    #pragma unroll
    for (int c = 0; c < 40; ++c) out[(size_t)i * 40 + c] = acc[c] - lg;
}

// ---------------- launch ----------------

extern "C" void kernel_launch(void* const* d_in, const int* in_sizes, int n_in,
                              void* d_out, int out_size, void* d_ws, size_t ws_size,
                              hipStream_t stream) {
    const float* x   = (const float*)d_in[0];
    const int*   ei  = (const int*)d_in[1];
    const float* W1a = (const float*)d_in[2];  const float* b1a = (const float*)d_in[3];
    const float* W1b = (const float*)d_in[4];  const float* b1b = (const float*)d_in[5];
    const float* W2a = (const float*)d_in[6];  const float* b2a = (const float*)d_in[7];
    const float* W2b = (const float*)d_in[8];  const float* b2b = (const float*)d_in[9];
    const float* W3a = (const float*)d_in[10]; const float* b3a = (const float*)d_in[11];
    const float* W3b = (const float*)d_in[12]; const float* b3b = (const float*)d_in[13];

    int N = in_sizes[0] / 512;
    int E = in_sizes[1] / 2;
    const int* srcv = ei;
    const int* dstv = ei + E;

    char* ws = (char*)d_ws;
    size_t off = 0;
    auto alloc = [&](size_t bytes) { void* p = ws + off; off = (off + bytes + 255) & ~(size_t)255; return p; };
    int*    cnt     = (int*)   alloc((size_t)N * 4);
    int*    cursor  = (int*)   alloc((size_t)N * 4);
    int*    offs    = (int*)   alloc((size_t)(N + 1) * 4);
    float*  dinv    = (float*) alloc((size_t)N * 4);
    int*    cursor8 = (int*)   alloc(8 * 4);
    int*    csr     = (int*)   alloc((size_t)E * 4);
    ushort* Wt      = (ushort*)alloc(128 * 512 * 2);
    float*  bcat    = (float*) alloc(128 * 4);
    float*  W3s     = (float*) alloc(1280 * 4);
    float*  b3s     = (float*) alloc(40 * 4);
    ushort* HWp     = (ushort*)alloc((size_t)N * 128 * 2);   // [N][128] bf16
    ushort* xsp     = (ushort*)alloc((size_t)N * 32 * 2);    // [N][32] bf16
    float*  axs     = (float*) alloc((size_t)N * 32 * 4);

    // bucket arrays alias HWp+xsp+axs region (dead until gemm; 2*E*4 <= N*128*2 + N*32*2 + N*32*4)
    int* bsrc = (int*)HWp;
    int* bdst = bsrc + E;

    hipMemsetAsync(cnt, 0, (size_t)N * 4, stream);
    hipMemsetAsync(cursor, 0, (size_t)N * 4, stream);

    count_kernel<<<2048, 256, 0, stream>>>(dstv, cnt, E);
    dinv_kernel<<<(N + 255) / 256, 256, 0, stream>>>(cnt, dinv, N);
    scan_kernel<<<1, 1024, 0, stream>>>(cnt, offs, N);
    init8_kernel<<<1, 8, 0, stream>>>(offs, cursor8, N);
    bucket_kernel<<<(E + BKE - 1) / BKE, 256, 0, stream>>>(srcv, dstv, cursor8, bsrc, bdst, E, N);
    scatter2_kernel<<<2048, 256, 0, stream>>>(bsrc, bdst, offs, cursor, csr, N);
    prep_kernel<<<256, 256, 0, stream>>>(W1a, W1b, W2a, W2b, b1a, b1b, b2a, b2b,
                                         W3a, W3b, b3a, b3b, Wt, bcat, W3s, b3s);
    gemm_mfma<<<(N + GBM - 1) / GBM, 256, 0, stream>>>(x, Wt, dinv, HWp, N);
    agg128<<<((size_t)N * 32 + 255) / 256, 256, 0, stream>>>(HWp, dinv, offs, csr, bcat, xsp, N);
    agg32<<<((size_t)N * 4 + 255) / 256, 256, 0, stream>>>(xsp, dinv, offs, csr, axs, N);
    final_kernel<<<(N + 255) / 256, 256, 0, stream>>>(axs, W3s, b3s, (float*)d_out, N);
}

// Round 9
// 543.049 us; speedup vs baseline: 1.1876x; 1.1876x over previous
//
#include <hip/hip_runtime.h>
#include <hip/hip_bf16.h>
#include <math.h>

typedef __attribute__((ext_vector_type(8))) short short8;
typedef __attribute__((ext_vector_type(4))) float f32x4;
typedef __attribute__((ext_vector_type(4))) int i32x4;

__device__ inline ushort f2bf(float f) {
    uint u = __builtin_bit_cast(uint, f);
    u += 0x7fffu + ((u >> 16) & 1u);          // round-to-nearest-even
    return (ushort)(u >> 16);
}
__device__ inline float bf2f(ushort h) {
    return __builtin_bit_cast(float, (uint)h << 16);
}

// ---------------- degree / CSR build ----------------

__global__ __launch_bounds__(256) void count_kernel(const int* __restrict__ dst, int* __restrict__ cnt, int E) {
    int t = blockIdx.x * blockDim.x + threadIdx.x;
    int stride = gridDim.x * blockDim.x;
    int E4 = E >> 2;
    const i32x4* d4 = (const i32x4*)dst;
    for (int e = t; e < E4; e += stride) {
        i32x4 v = d4[e];
        atomicAdd(&cnt[v.x], 1);
        atomicAdd(&cnt[v.y], 1);
        atomicAdd(&cnt[v.z], 1);
        atomicAdd(&cnt[v.w], 1);
    }
    for (int e = E4 * 4 + t; e < E; e += stride)
        atomicAdd(&cnt[dst[e]], 1);
}

__global__ __launch_bounds__(256) void dinv_kernel(const int* __restrict__ cnt, float* __restrict__ dinv, int N) {
    int i = blockIdx.x * 256 + threadIdx.x;
    if (i < N) dinv[i] = rsqrtf((float)(cnt[i] + 1));   // +1 self loop; deg >= 1 always
}

__global__ __launch_bounds__(1024) void scan_kernel(const int* __restrict__ cnt, int* __restrict__ offs, int N) {
    __shared__ int part[1024];
    int tid = threadIdx.x;
    int chunk = (((N + 1023) >> 10) + 3) & ~3;      // multiple of 4 -> aligned int4
    int beg = tid * chunk;
    int end = beg + chunk; if (end > N) end = N;
    int s = 0;
    int i = beg;
    for (; i + 3 < end; i += 4) {
        int4 v = *(const int4*)(cnt + i);
        s += v.x + v.y + v.z + v.w;
    }
    for (; i < end; ++i) s += cnt[i];
    part[tid] = s;
    __syncthreads();
    for (int off = 1; off < 1024; off <<= 1) {
        int t = (tid >= off) ? part[tid - off] : 0;
        __syncthreads();
        part[tid] += t;
        __syncthreads();
    }
    int run = (tid > 0) ? part[tid - 1] : 0;
    i = beg;
    for (; i + 3 < end; i += 4) {
        int4 v = *(const int4*)(cnt + i);
        offs[i] = run; run += v.x;
        offs[i + 1] = run; run += v.y;
        offs[i + 2] = run; run += v.z;
        offs[i + 3] = run; run += v.w;
    }
    for (; i < end; ++i) { offs[i] = run; run += cnt[i]; }
    if (beg < N && end == N) offs[N] = run;
}

// cursor256[b] = offs[lo_b] : append cursors for the 256 dst-range buckets
__global__ void init256_kernel(const int* __restrict__ offs, int* __restrict__ cursor256, int N) {
    int t = threadIdx.x;
    cursor256[t] = offs[(int)(((long long)N * t) >> 8)];
}

// ---------------- bucket pass: partition edges into 256 dst-range buckets (int2 pairs) -------
#define BKE 2048

__global__ __launch_bounds__(256) void bucket_kernel(const int* __restrict__ src, const int* __restrict__ dst,
                                                     int* __restrict__ cursor256, int2* __restrict__ epairs,
                                                     int E, int N, float recipN) {
    __shared__ int hist[256];
    __shared__ int base[256];
    int tid = threadIdx.x;
    int e0 = blockIdx.x * BKE;
    int e1 = e0 + BKE; if (e1 > E) e1 = E;
    if (e0 >= E) return;
    hist[tid] = 0;
    __syncthreads();
    int myd[8], mys[8], myg[8], myr[8];
    #pragma unroll
    for (int it = 0; it < 8; ++it) {
        int e = e0 + tid + it * 256;
        myg[it] = -1;
        if (e < e1) {
            int d = dst[e];
            int sv = src[e];
            int g = (int)((float)d * recipN);
            g = g < 0 ? 0 : (g > 255 ? 255 : g);
            while (d <  (int)(((long long)N * g) >> 8)) --g;
            while (d >= (int)(((long long)N * (g + 1)) >> 8)) ++g;
            myd[it] = d; mys[it] = sv; myg[it] = g;
            myr[it] = atomicAdd(&hist[g], 1);
        }
    }
    __syncthreads();
    base[tid] = atomicAdd(&cursor256[tid], hist[tid]);
    __syncthreads();
    #pragma unroll
    for (int it = 0; it < 8; ++it) {
        if (myg[it] >= 0) {
            int pos = base[myg[it]] + myr[it];
            epairs[pos] = make_int2(mys[it], myd[it]);   // (src, dst)
        }
    }
}

// ---------------- sort pass: one block per bucket, LDS counting-scatter, sequential csr out ----
#define MAXBE 16384

__global__ __launch_bounds__(256) void sortcsr_kernel(const int2* __restrict__ epairs,
                                                      const int* __restrict__ offs,
                                                      int* __restrict__ csr, int N) {
    __shared__ int lcur[512];
    __shared__ int lcsr[MAXBE];
    int b = blockIdx.x;
    int lo = (int)(((long long)N * b) >> 8);
    int hi = (int)(((long long)N * (b + 1)) >> 8);
    int eb = offs[lo], ee = offs[hi];
    int nloc = hi - lo;
    int tid = threadIdx.x;
    for (int t = tid; t < nloc; t += 256) lcur[t] = offs[lo + t] - eb;
    __syncthreads();
    for (int e = eb + tid; e < ee; e += 256) {
        int2 p = epairs[e];
        int pos = atomicAdd(&lcur[p.y - lo], 1);
        if (pos < MAXBE) lcsr[pos] = p.x;
        else csr[eb + pos] = p.x;      // statistically-unreachable overflow fallback
    }
    __syncthreads();
    int ne = ee - eb; if (ne > MAXBE) ne = MAXBE;
    for (int e = tid; e < ne; e += 256) csr[eb + e] = lcsr[e];
}

// ---------------- weight prep: Wt[128][512] bf16 (transposed), bcat[128], W3s[32*40], b3s[40] ----

__global__ __launch_bounds__(256) void prep_kernel(const float* __restrict__ W1a, const float* __restrict__ W1b,
                                                   const float* __restrict__ W2a, const float* __restrict__ W2b,
                                                   const float* __restrict__ b1a, const float* __restrict__ b1b,
                                                   const float* __restrict__ b2a, const float* __restrict__ b2b,
                                                   const float* __restrict__ W3a, const float* __restrict__ W3b,
                                                   const float* __restrict__ b3a, const float* __restrict__ b3b,
                                                   ushort* __restrict__ Wt, float* __restrict__ bcat,
                                                   float* __restrict__ W3s, float* __restrict__ b3s) {
    int idx = blockIdx.x * 256 + threadIdx.x;
    if (idx < 128 * 512) {
        int c = idx >> 9, k = idx & 511;   // Wt[c][k] = Wcat[k][c]
        const float* W = (c < 32) ? W1a : (c < 64) ? W1b : (c < 96) ? W2a : W2b;
        Wt[idx] = f2bf(W[k * 32 + (c & 31)]);
    }
    if (idx < 1280) W3s[idx] = W3a[idx] + W3b[idx];
    if (idx < 128) {
        const float* b = (idx < 32) ? b1a : (idx < 64) ? b1b : (idx < 96) ? b2a : b2b;
        bcat[idx] = b[idx & 31];
    }
    if (idx < 40) b3s[idx] = b3a[idx] + b3b[idx];
}

// ---------------- MFMA GEMM: HWp[N][128] = bf16( (X@Wcat)[r][c] * dinv[r] ) ----------------

#define GBM 64

__global__ __launch_bounds__(256) void gemm_mfma(const float* __restrict__ X,
                                                 const ushort* __restrict__ Wt,
                                                 const float* __restrict__ dinv,
                                                 ushort* __restrict__ HWp, int N) {
    __shared__ ushort Alds[2][64 * 64];    // [buf][row][k] 16B chunks swz: c' = c ^ (row&7)
    __shared__ ushort Blds[2][128 * 64];
    const int tid = threadIdx.x;
    const int lane = tid & 63;
    const int wave = tid >> 6;
    const int rQ = lane & 15, g = lane >> 4;
    const int swz = rQ & 7;
    const int rowBase = blockIdx.x * GBM;

    const int ar = tid >> 2, aq = tid & 3;
    int arow = rowBase + ar; if (arow > N - 1) arow = N - 1;
    const float* aglob = X + (size_t)arow * 512 + aq * 4;

    const int br = tid >> 1, bh = tid & 1;
    const ushort* bglob = Wt + (size_t)br * 512 + bh * 32;

    float4 a4[4];
    uint4 b4[4];
    f32x4 acc[4][2] = {};

#define LOAD_REGS(k0)                                                       \
    {                                                                       \
        _Pragma("unroll")                                                   \
        for (int i = 0; i < 4; ++i) a4[i] = *(const float4*)(aglob + (k0) + i * 16); \
        _Pragma("unroll")                                                   \
        for (int i = 0; i < 4; ++i) b4[i] = *(const uint4*)(bglob + (k0) + i * 8);   \
    }

#define WRITE_LDS(buf)                                                      \
    {                                                                       \
        _Pragma("unroll")                                                   \
        for (int i = 0; i < 4; ++i) {                                       \
            int c = i * 2 + (aq >> 1);                                      \
            ushort4 u; u.x = f2bf(a4[i].x); u.y = f2bf(a4[i].y);            \
            u.z = f2bf(a4[i].z); u.w = f2bf(a4[i].w);                       \
            *(ushort4*)(&Alds[buf][ar * 64 + ((c ^ (ar & 7)) << 3) + (aq & 1) * 4]) = u; \
        }                                                                   \
        ushort* bp = &Blds[buf][br * 64];                                   \
        _Pragma("unroll")                                                   \
        for (int i = 0; i < 4; ++i) {                                       \
            int c = bh * 4 + i;                                             \
            *(uint4*)(bp + ((c ^ (br & 7)) << 3)) = b4[i];                  \
        }                                                                   \
    }

#define COMPUTE(buf)                                                        \
    {                                                                       \
        short8 bf[2][2];                                                    \
        _Pragma("unroll")                                                   \
        for (int ct2 = 0; ct2 < 2; ++ct2) {                                 \
            int brow = wave * 32 + ct2 * 16 + rQ;                           \
            _Pragma("unroll")                                               \
            for (int sub = 0; sub < 2; ++sub)                               \
                bf[ct2][sub] = *(const short8*)(&Blds[buf][brow * 64 + (((sub * 4 + g) ^ swz) << 3)]); \
        }                                                                   \
        _Pragma("unroll")                                                   \
        for (int rt = 0; rt < 4; ++rt) {                                    \
            int arw = rt * 16 + rQ;                                         \
            _Pragma("unroll")                                               \
            for (int sub = 0; sub < 2; ++sub) {                             \
                short8 af = *(const short8*)(&Alds[buf][arw * 64 + (((sub * 4 + g) ^ swz) << 3)]); \
                _Pragma("unroll")                                           \
                for (int ct2 = 0; ct2 < 2; ++ct2)                           \
                    acc[rt][ct2] = __builtin_amdgcn_mfma_f32_16x16x32_bf16( \
                        af, bf[ct2][sub], acc[rt][ct2], 0, 0, 0);           \
            }                                                               \
        }                                                                   \
    }

    LOAD_REGS(0);
    WRITE_LDS(0);
    for (int s = 0; s < 8; ++s) {
        __syncthreads();
        if (s + 1 < 8) LOAD_REGS((s + 1) * 64);
        COMPUTE(s & 1);
        if (s + 1 < 8) {
            __syncthreads();
            WRITE_LDS((s + 1) & 1);
        }
    }

    #pragma unroll
    for (int rt = 0; rt < 4; ++rt) {
        #pragma unroll
        for (int j = 0; j < 4; ++j) {
            int r = rowBase + rt * 16 + g * 4 + j;
            if (r < N) {
                float dv = dinv[r];
                #pragma unroll
                for (int ct2 = 0; ct2 < 2; ++ct2) {
                    int c = wave * 32 + ct2 * 16 + rQ;
                    HWp[(size_t)r * 128 + c] = f2bf(acc[rt][ct2][j] * dv);
                }
            }
        }
    }
#undef LOAD_REGS
#undef WRITE_LDS
#undef COMPUTE
}

// ---------------- aggregation 128 (bf16 gather, unroll-4 MLP) + fused relu/bias/block-sum ----------

__global__ __launch_bounds__(256) void agg128(const ushort* __restrict__ HWp, const float* __restrict__ dinv,
                                              const int* __restrict__ offs, const int* __restrict__ csr,
                                              const float* __restrict__ bcat, ushort* __restrict__ xsp, int N) {
    int t = blockIdx.x * 256 + threadIdx.x;
    int node = t >> 5, c = t & 31;      // lane c holds features 4c..4c+3
    if (node >= N) return;
    const ushort4* H = (const ushort4*)HWp;
    ushort4 h = H[(size_t)node * 32 + c];
    float a0 = bf2f(h.x), a1 = bf2f(h.y), a2 = bf2f(h.z), a3 = bf2f(h.w);
    int j = offs[node];
    int e1 = offs[node + 1];
    int jend = j + ((e1 - j) & ~3);
    for (; j < jend; j += 4) {
        int s0 = csr[j], s1 = csr[j + 1], s2 = csr[j + 2], s3 = csr[j + 3];
        ushort4 v0 = H[(size_t)s0 * 32 + c];
        ushort4 v1 = H[(size_t)s1 * 32 + c];
        ushort4 v2 = H[(size_t)s2 * 32 + c];
        ushort4 v3 = H[(size_t)s3 * 32 + c];
        a0 += bf2f(v0.x) + bf2f(v1.x) + bf2f(v2.x) + bf2f(v3.x);
        a1 += bf2f(v0.y) + bf2f(v1.y) + bf2f(v2.y) + bf2f(v3.y);
        a2 += bf2f(v0.z) + bf2f(v1.z) + bf2f(v2.z) + bf2f(v3.z);
        a3 += bf2f(v0.w) + bf2f(v1.w) + bf2f(v2.w) + bf2f(v3.w);
    }
    for (; j < e1; ++j) {
        int s = csr[j];
        ushort4 v = H[(size_t)s * 32 + c];
        a0 += bf2f(v.x); a1 += bf2f(v.y); a2 += bf2f(v.z); a3 += bf2f(v.w);
    }
    float di = dinv[node];
    float4 b = *(const float4*)(bcat + c * 4);
    float r0 = fmaxf(di * a0 + b.x, 0.f);
    float r1 = fmaxf(di * a1 + b.y, 0.f);
    float r2 = fmaxf(di * a2 + b.z, 0.f);
    float r3 = fmaxf(di * a3 + b.w, 0.f);
    r0 += __shfl_xor(r0, 8);  r1 += __shfl_xor(r1, 8);  r2 += __shfl_xor(r2, 8);  r3 += __shfl_xor(r3, 8);
    r0 += __shfl_xor(r0, 16); r1 += __shfl_xor(r1, 16); r2 += __shfl_xor(r2, 16); r3 += __shfl_xor(r3, 16);
    if ((c & 24) == 0) {
        ushort4 o;
        o.x = f2bf(r0 * di); o.y = f2bf(r1 * di); o.z = f2bf(r2 * di); o.w = f2bf(r3 * di);
        *(ushort4*)(xsp + (size_t)node * 32 + c * 4) = o;
    }
}

// ---------------- aggregation 32 (bf16 gather, unroll-4 MLP) -> axs f32 ----------------

__global__ __launch_bounds__(256) void agg32(const ushort* __restrict__ xsp, const float* __restrict__ dinv,
                                             const int* __restrict__ offs, const int* __restrict__ csr,
                                             float* __restrict__ axs, int N) {
    int t = blockIdx.x * 256 + threadIdx.x;
    int node = t >> 2, l = t & 3;
    if (node >= N) return;
    const short8* Xr = (const short8*)xsp;   // [N][4] chunks of 8 bf16
    short8 h = Xr[(size_t)node * 4 + l];
    float a[8];
    #pragma unroll
    for (int i = 0; i < 8; ++i) a[i] = bf2f((ushort)h[i]);
    int j = offs[node];
    int e1 = offs[node + 1];
    int jend = j + ((e1 - j) & ~3);
    for (; j < jend; j += 4) {
        int s0 = csr[j], s1 = csr[j + 1], s2 = csr[j + 2], s3 = csr[j + 3];
        short8 v0 = Xr[(size_t)s0 * 4 + l];
        short8 v1 = Xr[(size_t)s1 * 4 + l];
        short8 v2 = Xr[(size_t)s2 * 4 + l];
        short8 v3 = Xr[(size_t)s3 * 4 + l];
        #pragma unroll
        for (int i = 0; i < 8; ++i)
            a[i] += bf2f((ushort)v0[i]) + bf2f((ushort)v1[i]) + bf2f((ushort)v2[i]) + bf2f((ushort)v3[i]);
    }
    for (; j < e1; ++j) {
        int s = csr[j];
        short8 v = Xr[(size_t)s * 4 + l];
        #pragma unroll
        for (int i = 0; i < 8; ++i) a[i] += bf2f((ushort)v[i]);
    }
    float di = dinv[node];
    float4 o0 = make_float4(a[0] * di, a[1] * di, a[2] * di, a[3] * di);
    float4 o1 = make_float4(a[4] * di, a[5] * di, a[6] * di, a[7] * di);
    float* dst = axs + (size_t)node * 32 + l * 8;
    *(float4*)dst = o0;
    *(float4*)(dst + 4) = o1;
}

// ---------------- final: logits = axs @ W3s + b3s ; log_softmax ----------------

__global__ __launch_bounds__(256) void final_kernel(const float* __restrict__ axs, const float* __restrict__ W3s,
                                                    const float* __restrict__ b3s, float* __restrict__ out, int N) {
    __shared__ float w[32 * 40];
    __shared__ float b[40];
    int tid = threadIdx.x;
    for (int i = tid; i < 1280; i += 256) w[i] = W3s[i];
    if (tid < 40) b[tid] = b3s[tid];
    __syncthreads();
    int i = blockIdx.x * 256 + tid;
    if (i >= N) return;
    float a[32];
    #pragma unroll
    for (int q = 0; q < 8; ++q) {
        float4 v = *(const float4*)(axs + (size_t)i * 32 + q * 4);
        a[q * 4] = v.x; a[q * 4 + 1] = v.y; a[q * 4 + 2] = v.z; a[q * 4 + 3] = v.w;
    }
    float acc[40];
    #pragma unroll
    for (int c = 0; c < 40; ++c) acc[c] = b[c];
    #pragma unroll
    for (int k = 0; k < 32; ++k) {
        float av = a[k];
        #pragma unroll
        for (int c = 0; c < 40; ++c) acc[c] += av * w[k * 40 + c];
    }
    float m = acc[0];
    #pragma unroll
    for (int c = 1; c < 40; ++c) m = fmaxf(m, acc[c]);
    float sum = 0.f;
    #pragma unroll
    for (int c = 0; c < 40; ++c) sum += expf(acc[c] - m);
    float lg = m + logf(sum);
    #pragma unroll
    for (int c = 0; c < 40; ++c) out[(size_t)i * 40 + c] = acc[c] - lg;
}

// ---------------- launch ----------------

extern "C" void kernel_launch(void* const* d_in, const int* in_sizes, int n_in,
                              void* d_out, int out_size, void* d_ws, size_t ws_size,
                              hipStream_t stream) {
    const float* x   = (const float*)d_in[0];
    const int*   ei  = (const int*)d_in[1];
    const float* W1a = (const float*)d_in[2];  const float* b1a = (const float*)d_in[3];
    const float* W1b = (const float*)d_in[4];  const float* b1b = (const float*)d_in[5];
    const float* W2a = (const float*)d_in[6];  const float* b2a = (const float*)d_in[7];
    const float* W2b = (const float*)d_in[8];  const float* b2b = (const float*)d_in[9];
    const float* W3a = (const float*)d_in[10]; const float* b3a = (const float*)d_in[11];
    const float* W3b = (const float*)d_in[12]; const float* b3b = (const float*)d_in[13];

    int N = in_sizes[0] / 512;
    int E = in_sizes[1] / 2;
    const int* srcv = ei;
    const int* dstv = ei + E;

    char* ws = (char*)d_ws;
    size_t off = 0;
    auto alloc = [&](size_t bytes) { void* p = ws + off; off = (off + bytes + 255) & ~(size_t)255; return p; };
    int*    cnt      = (int*)   alloc((size_t)N * 4);
    int*    offs     = (int*)   alloc((size_t)(N + 1) * 4);
    float*  dinv     = (float*) alloc((size_t)N * 4);
    int*    cursor256= (int*)   alloc(256 * 4);
    int*    csr      = (int*)   alloc((size_t)E * 4);
    ushort* Wt       = (ushort*)alloc(128 * 512 * 2);
    float*  bcat     = (float*) alloc(128 * 4);
    float*  W3s      = (float*) alloc(1280 * 4);
    float*  b3s      = (float*) alloc(40 * 4);
    ushort* HWp      = (ushort*)alloc((size_t)N * 128 * 2);   // [N][128] bf16
    ushort* xsp      = (ushort*)alloc((size_t)N * 32 * 2);    // [N][32] bf16
    float*  axs      = (float*) alloc((size_t)N * 32 * 4);

    // epairs aliases HWp (dead until gemm; E*8 == N*128*2 for this shape)
    int2* epairs = (int2*)HWp;

    hipMemsetAsync(cnt, 0, (size_t)N * 4, stream);

    count_kernel<<<2048, 256, 0, stream>>>(dstv, cnt, E);
    dinv_kernel<<<(N + 255) / 256, 256, 0, stream>>>(cnt, dinv, N);
    scan_kernel<<<1, 1024, 0, stream>>>(cnt, offs, N);
    init256_kernel<<<1, 256, 0, stream>>>(offs, cursor256, N);
    bucket_kernel<<<(E + BKE - 1) / BKE, 256, 0, stream>>>(srcv, dstv, cursor256, epairs, E, N,
                                                           256.0f / (float)N);
    sortcsr_kernel<<<256, 256, 0, stream>>>(epairs, offs, csr, N);
    prep_kernel<<<256, 256, 0, stream>>>(W1a, W1b, W2a, W2b, b1a, b1b, b2a, b2b,
                                         W3a, W3b, b3a, b3b, Wt, bcat, W3s, b3s);
    gemm_mfma<<<(N + GBM - 1) / GBM, 256, 0, stream>>>(x, Wt, dinv, HWp, N);
    agg128<<<((size_t)N * 32 + 255) / 256, 256, 0, stream>>>(HWp, dinv, offs, csr, bcat, xsp, N);
    agg32<<<((size_t)N * 4 + 255) / 256, 256, 0, stream>>>(xsp, dinv, offs, csr, axs, N);
    final_kernel<<<(N + 255) / 256, 256, 0, stream>>>(axs, W3s, b3s, (float*)d_out, N);
}

// Round 10
// 388.449 us; speedup vs baseline: 1.6603x; 1.3980x over previous
//
#include <hip/hip_runtime.h>
#include <hip/hip_bf16.h>
#include <math.h>

typedef __attribute__((ext_vector_type(8))) short short8;
typedef __attribute__((ext_vector_type(4))) float f32x4;

__device__ inline ushort f2bf(float f) {
    uint u = __builtin_bit_cast(uint, f);
    u += 0x7fffu + ((u >> 16) & 1u);          // round-to-nearest-even
    return (ushort)(u >> 16);
}
__device__ inline float bf2f(ushort h) {
    return __builtin_bit_cast(float, (uint)h << 16);
}

// ================= CSR build: bucket counting-sort, zero global per-node atomics ==========
// Buckets: 256 node ranges of width W = ceil(N/256) (requires W <= 512, N <= 131072).
// Edge packed as src | ((d - bucket_lo) << 17)  (src < 2^17, local idx < 2^9).

#define NB   256
#define CNTB 1024
#define BKE  2048
#define MAXBE 16384

__device__ inline int bucket_of(int d, int W, float recipW) {
    int g = (int)((float)d * recipW);
    if (g > NB - 1) g = NB - 1;
    while (d < g * W) --g;
    while (d >= (g + 1) * W) ++g;
    return g;
}

__global__ __launch_bounds__(256) void bucketcnt_kernel(const int* __restrict__ dst,
                                                        int* __restrict__ bcntpart,
                                                        int E, int W, float recipW) {
    __shared__ int hist[NB];
    int tid = threadIdx.x;
    hist[tid] = 0;
    __syncthreads();
    int per = (E + CNTB - 1) / CNTB;
    int e0 = blockIdx.x * per;
    int e1 = e0 + per; if (e1 > E) e1 = E;
    for (int e = e0 + tid; e < e1; e += 256)
        atomicAdd(&hist[bucket_of(dst[e], W, recipW)], 1);
    __syncthreads();
    bcntpart[blockIdx.x * NB + tid] = hist[tid];
}

__global__ __launch_bounds__(256) void scan256_kernel(const int* __restrict__ bcntpart,
                                                      int* __restrict__ bbase,
                                                      int* __restrict__ cursor256) {
    __shared__ int tot[NB];
    int b = threadIdx.x;
    int s = 0;
    for (int i = 0; i < CNTB; ++i) s += bcntpart[i * NB + b];
    int val = s;
    tot[b] = s;
    __syncthreads();
    for (int off = 1; off < NB; off <<= 1) {
        int t = (b >= off) ? tot[b - off] : 0;
        __syncthreads();
        tot[b] += t;
        __syncthreads();
    }
    int excl = tot[b] - val;
    bbase[b] = excl;
    cursor256[b] = excl;
    if (b == NB - 1) bbase[NB] = tot[NB - 1];
}

__global__ __launch_bounds__(256) void bucket_kernel(const int* __restrict__ src, const int* __restrict__ dst,
                                                     int* __restrict__ cursor256, int* __restrict__ epk,
                                                     int E, int W, float recipW) {
    __shared__ int hist[NB];
    __shared__ int base[NB];
    int tid = threadIdx.x;
    int e0 = blockIdx.x * BKE;
    int e1 = e0 + BKE; if (e1 > E) e1 = E;
    if (e0 >= E) return;
    hist[tid] = 0;
    __syncthreads();
    int myp[8], myg[8], myr[8];
    #pragma unroll
    for (int it = 0; it < 8; ++it) {
        int e = e0 + tid + it * 256;
        myg[it] = -1;
        if (e < e1) {
            int d = dst[e];
            int g = bucket_of(d, W, recipW);
            myp[it] = src[e] | ((d - g * W) << 17);
            myg[it] = g;
            myr[it] = atomicAdd(&hist[g], 1);
        }
    }
    __syncthreads();
    base[tid] = atomicAdd(&cursor256[tid], hist[tid]);
    __syncthreads();
    #pragma unroll
    for (int it = 0; it < 8; ++it)
        if (myg[it] >= 0)
            epk[base[myg[it]] + myr[it]] = myp[it];
}

// one block per bucket: LDS histogram -> scan -> offs/dinv out -> LDS counting-scatter -> csr
__global__ __launch_bounds__(256) void sortcsr_kernel(const int* __restrict__ epk,
                                                      const int* __restrict__ bbase,
                                                      int* __restrict__ csr, int* __restrict__ offs,
                                                      float* __restrict__ dinv, int N, int W, int E) {
    __shared__ int lcnt[512];
    __shared__ int lofs[513];
    __shared__ int tmp[256];
    __shared__ int lcsr[MAXBE];
    int b = blockIdx.x;
    int lo = b * W;
    int nloc = N - lo; if (nloc > W) nloc = W; if (nloc < 0) nloc = 0;
    int eb = bbase[b], ee = bbase[b + 1];
    int tid = threadIdx.x;
    lcnt[2 * tid] = 0; lcnt[2 * tid + 1] = 0;
    __syncthreads();
    for (int e = eb + tid; e < ee; e += 256)
        atomicAdd(&lcnt[epk[e] >> 17], 1);
    __syncthreads();
    // exclusive scan over 512 entries (2 per thread)
    int a0 = lcnt[2 * tid], a1 = lcnt[2 * tid + 1];
    int psum = a0 + a1;
    tmp[tid] = psum;
    __syncthreads();
    for (int off = 1; off < 256; off <<= 1) {
        int t = (tid >= off) ? tmp[tid - off] : 0;
        __syncthreads();
        tmp[tid] += t;
        __syncthreads();
    }
    int excl = tmp[tid] - psum;
    lofs[2 * tid] = excl;
    lofs[2 * tid + 1] = excl + a0;
    lcnt[2 * tid] = excl;          // reset as cursor
    lcnt[2 * tid + 1] = excl + a0;
    if (tid == 255) lofs[512] = tmp[255];
    __syncthreads();
    // emit offs + dinv
    for (int t = tid; t < nloc; t += 256) {
        offs[lo + t] = eb + lofs[t];
        int deg = lofs[t + 1] - lofs[t];
        dinv[lo + t] = rsqrtf((float)(deg + 1));
    }
    if (b == NB - 1 && tid == 0) offs[N] = E;
    // counting scatter into LDS, then sequential stream-out
    for (int e = eb + tid; e < ee; e += 256) {
        int p = epk[e];
        int pos = atomicAdd(&lcnt[p >> 17], 1);
        int sv = p & 0x1FFFF;
        if (pos < MAXBE) lcsr[pos] = sv;
        else csr[eb + pos] = sv;       // statistically-unreachable overflow fallback
    }
    __syncthreads();
    int ne = ee - eb; if (ne > MAXBE) ne = MAXBE;
    for (int e = tid; e < ne; e += 256) csr[eb + e] = lcsr[e];
}

// ---------------- weight prep: Wt[128][512] bf16 (transposed), bcat[128], W3s[32*40], b3s[40] ----

__global__ __launch_bounds__(256) void prep_kernel(const float* __restrict__ W1a, const float* __restrict__ W1b,
                                                   const float* __restrict__ W2a, const float* __restrict__ W2b,
                                                   const float* __restrict__ b1a, const float* __restrict__ b1b,
                                                   const float* __restrict__ b2a, const float* __restrict__ b2b,
                                                   const float* __restrict__ W3a, const float* __restrict__ W3b,
                                                   const float* __restrict__ b3a, const float* __restrict__ b3b,
                                                   ushort* __restrict__ Wt, float* __restrict__ bcat,
                                                   float* __restrict__ W3s, float* __restrict__ b3s) {
    int idx = blockIdx.x * 256 + threadIdx.x;
    if (idx < 128 * 512) {
        int c = idx >> 9, k = idx & 511;   // Wt[c][k] = Wcat[k][c]
        const float* W = (c < 32) ? W1a : (c < 64) ? W1b : (c < 96) ? W2a : W2b;
        Wt[idx] = f2bf(W[k * 32 + (c & 31)]);
    }
    if (idx < 1280) W3s[idx] = W3a[idx] + W3b[idx];
    if (idx < 128) {
        const float* b = (idx < 32) ? b1a : (idx < 64) ? b1b : (idx < 96) ? b2a : b2b;
        bcat[idx] = b[idx & 31];
    }
    if (idx < 40) b3s[idx] = b3a[idx] + b3b[idx];
}

// ---------------- MFMA GEMM: HWp[N][128] = bf16( (X@Wcat)[r][c] * dinv[r] ) ----------------

#define GBM 64

__global__ __launch_bounds__(256) void gemm_mfma(const float* __restrict__ X,
                                                 const ushort* __restrict__ Wt,
                                                 const float* __restrict__ dinv,
                                                 ushort* __restrict__ HWp, int N) {
    __shared__ ushort Alds[2][64 * 64];    // [buf][row][k] 16B chunks swz: c' = c ^ (row&7)
    __shared__ ushort Blds[2][128 * 64];
    const int tid = threadIdx.x;
    const int lane = tid & 63;
    const int wave = tid >> 6;
    const int rQ = lane & 15, g = lane >> 4;
    const int swz = rQ & 7;
    const int rowBase = blockIdx.x * GBM;

    const int ar = tid >> 2, aq = tid & 3;
    int arow = rowBase + ar; if (arow > N - 1) arow = N - 1;
    const float* aglob = X + (size_t)arow * 512 + aq * 4;

    const int br = tid >> 1, bh = tid & 1;
    const ushort* bglob = Wt + (size_t)br * 512 + bh * 32;

    float4 a4[4];
    uint4 b4[4];
    f32x4 acc[4][2] = {};

#define LOAD_REGS(k0)                                                       \
    {                                                                       \
        _Pragma("unroll")                                                   \
        for (int i = 0; i < 4; ++i) a4[i] = *(const float4*)(aglob + (k0) + i * 16); \
        _Pragma("unroll")                                                   \
        for (int i = 0; i < 4; ++i) b4[i] = *(const uint4*)(bglob + (k0) + i * 8);   \
    }

#define WRITE_LDS(buf)                                                      \
    {                                                                       \
        _Pragma("unroll")                                                   \
        for (int i = 0; i < 4; ++i) {                                       \
            int c = i * 2 + (aq >> 1);                                      \
            ushort4 u; u.x = f2bf(a4[i].x); u.y = f2bf(a4[i].y);            \
            u.z = f2bf(a4[i].z); u.w = f2bf(a4[i].w);                       \
            *(ushort4*)(&Alds[buf][ar * 64 + ((c ^ (ar & 7)) << 3) + (aq & 1) * 4]) = u; \
        }                                                                   \
        ushort* bp = &Blds[buf][br * 64];                                   \
        _Pragma("unroll")                                                   \
        for (int i = 0; i < 4; ++i) {                                       \
            int c = bh * 4 + i;                                             \
            *(uint4*)(bp + ((c ^ (br & 7)) << 3)) = b4[i];                  \
        }                                                                   \
    }

#define COMPUTE(buf)                                                        \
    {                                                                       \
        short8 bf[2][2];                                                    \
        _Pragma("unroll")                                                   \
        for (int ct2 = 0; ct2 < 2; ++ct2) {                                 \
            int brow = wave * 32 + ct2 * 16 + rQ;                           \
            _Pragma("unroll")                                               \
            for (int sub = 0; sub < 2; ++sub)                               \
                bf[ct2][sub] = *(const short8*)(&Blds[buf][brow * 64 + (((sub * 4 + g) ^ swz) << 3)]); \
        }                                                                   \
        _Pragma("unroll")                                                   \
        for (int rt = 0; rt < 4; ++rt) {                                    \
            int arw = rt * 16 + rQ;                                         \
            _Pragma("unroll")                                               \
            for (int sub = 0; sub < 2; ++sub) {                             \
                short8 af = *(const short8*)(&Alds[buf][arw * 64 + (((sub * 4 + g) ^ swz) << 3)]); \
                _Pragma("unroll")                                           \
                for (int ct2 = 0; ct2 < 2; ++ct2)                           \
                    acc[rt][ct2] = __builtin_amdgcn_mfma_f32_16x16x32_bf16( \
                        af, bf[ct2][sub], acc[rt][ct2], 0, 0, 0);           \
            }                                                               \
        }                                                                   \
    }

    LOAD_REGS(0);
    WRITE_LDS(0);
    for (int s = 0; s < 8; ++s) {
        __syncthreads();
        if (s + 1 < 8) LOAD_REGS((s + 1) * 64);
        COMPUTE(s & 1);
        if (s + 1 < 8) {
            __syncthreads();
            WRITE_LDS((s + 1) & 1);
        }
    }

    #pragma unroll
    for (int rt = 0; rt < 4; ++rt) {
        #pragma unroll
        for (int j = 0; j < 4; ++j) {
            int r = rowBase + rt * 16 + g * 4 + j;
            if (r < N) {
                float dv = dinv[r];
                #pragma unroll
                for (int ct2 = 0; ct2 < 2; ++ct2) {
                    int c = wave * 32 + ct2 * 16 + rQ;
                    HWp[(size_t)r * 128 + c] = f2bf(acc[rt][ct2][j] * dv);
                }
            }
        }
    }
#undef LOAD_REGS
#undef WRITE_LDS
#undef COMPUTE
}

// ---------------- aggregation 128 (bf16 gather, unroll-4 MLP) + fused relu/bias/block-sum ----------

__global__ __launch_bounds__(256) void agg128(const ushort* __restrict__ HWp, const float* __restrict__ dinv,
                                              const int* __restrict__ offs, const int* __restrict__ csr,
                                              const float* __restrict__ bcat, ushort* __restrict__ xsp, int N) {
    int t = blockIdx.x * 256 + threadIdx.x;
    int node = t >> 5, c = t & 31;      // lane c holds features 4c..4c+3
    if (node >= N) return;
    const ushort4* H = (const ushort4*)HWp;
    ushort4 h = H[(size_t)node * 32 + c];
    float a0 = bf2f(h.x), a1 = bf2f(h.y), a2 = bf2f(h.z), a3 = bf2f(h.w);
    int j = offs[node];
    int e1 = offs[node + 1];
    int jend = j + ((e1 - j) & ~3);
    for (; j < jend; j += 4) {
        int s0 = csr[j], s1 = csr[j + 1], s2 = csr[j + 2], s3 = csr[j + 3];
        ushort4 v0 = H[(size_t)s0 * 32 + c];
        ushort4 v1 = H[(size_t)s1 * 32 + c];
        ushort4 v2 = H[(size_t)s2 * 32 + c];
        ushort4 v3 = H[(size_t)s3 * 32 + c];
        a0 += bf2f(v0.x) + bf2f(v1.x) + bf2f(v2.x) + bf2f(v3.x);
        a1 += bf2f(v0.y) + bf2f(v1.y) + bf2f(v2.y) + bf2f(v3.y);
        a2 += bf2f(v0.z) + bf2f(v1.z) + bf2f(v2.z) + bf2f(v3.z);
        a3 += bf2f(v0.w) + bf2f(v1.w) + bf2f(v2.w) + bf2f(v3.w);
    }
    for (; j < e1; ++j) {
        int s = csr[j];
        ushort4 v = H[(size_t)s * 32 + c];
        a0 += bf2f(v.x); a1 += bf2f(v.y); a2 += bf2f(v.z); a3 += bf2f(v.w);
    }
    float di = dinv[node];
    float4 b = *(const float4*)(bcat + c * 4);
    float r0 = fmaxf(di * a0 + b.x, 0.f);
    float r1 = fmaxf(di * a1 + b.y, 0.f);
    float r2 = fmaxf(di * a2 + b.z, 0.f);
    float r3 = fmaxf(di * a3 + b.w, 0.f);
    r0 += __shfl_xor(r0, 8);  r1 += __shfl_xor(r1, 8);  r2 += __shfl_xor(r2, 8);  r3 += __shfl_xor(r3, 8);
    r0 += __shfl_xor(r0, 16); r1 += __shfl_xor(r1, 16); r2 += __shfl_xor(r2, 16); r3 += __shfl_xor(r3, 16);
    if ((c & 24) == 0) {
        ushort4 o;
        o.x = f2bf(r0 * di); o.y = f2bf(r1 * di); o.z = f2bf(r2 * di); o.w = f2bf(r3 * di);
        *(ushort4*)(xsp + (size_t)node * 32 + c * 4) = o;
    }
}

// ---------------- aggregation 32 (bf16 gather, unroll-4 MLP) -> axs f32 ----------------

__global__ __launch_bounds__(256) void agg32(const ushort* __restrict__ xsp, const float* __restrict__ dinv,
                                             const int* __restrict__ offs, const int* __restrict__ csr,
                                             float* __restrict__ axs, int N) {
    int t = blockIdx.x * 256 + threadIdx.x;
    int node = t >> 2, l = t & 3;
    if (node >= N) return;
    const short8* Xr = (const short8*)xsp;   // [N][4] chunks of 8 bf16
    short8 h = Xr[(size_t)node * 4 + l];
    float a[8];
    #pragma unroll
    for (int i = 0; i < 8; ++i) a[i] = bf2f((ushort)h[i]);
    int j = offs[node];
    int e1 = offs[node + 1];
    int jend = j + ((e1 - j) & ~3);
    for (; j < jend; j += 4) {
        int s0 = csr[j], s1 = csr[j + 1], s2 = csr[j + 2], s3 = csr[j + 3];
        short8 v0 = Xr[(size_t)s0 * 4 + l];
        short8 v1 = Xr[(size_t)s1 * 4 + l];
        short8 v2 = Xr[(size_t)s2 * 4 + l];
        short8 v3 = Xr[(size_t)s3 * 4 + l];
        #pragma unroll
        for (int i = 0; i < 8; ++i)
            a[i] += bf2f((ushort)v0[i]) + bf2f((ushort)v1[i]) + bf2f((ushort)v2[i]) + bf2f((ushort)v3[i]);
    }
    for (; j < e1; ++j) {
        int s = csr[j];
        short8 v = Xr[(size_t)s * 4 + l];
        #pragma unroll
        for (int i = 0; i < 8; ++i) a[i] += bf2f((ushort)v[i]);
    }
    float di = dinv[node];
    float4 o0 = make_float4(a[0] * di, a[1] * di, a[2] * di, a[3] * di);
    float4 o1 = make_float4(a[4] * di, a[5] * di, a[6] * di, a[7] * di);
    float* dst = axs + (size_t)node * 32 + l * 8;
    *(float4*)dst = o0;
    *(float4*)(dst + 4) = o1;
}

// ---------------- final: logits = axs @ W3s + b3s ; log_softmax ----------------

__global__ __launch_bounds__(256) void final_kernel(const float* __restrict__ axs, const float* __restrict__ W3s,
                                                    const float* __restrict__ b3s, float* __restrict__ out, int N) {
    __shared__ float w[32 * 40];
    __shared__ float b[40];
    int tid = threadIdx.x;
    for (int i = tid; i < 1280; i += 256) w[i] = W3s[i];
    if (tid < 40) b[tid] = b3s[tid];
    __syncthreads();
    int i = blockIdx.x * 256 + tid;
    if (i >= N) return;
    float a[32];
    #pragma unroll
    for (int q = 0; q < 8; ++q) {
        float4 v = *(const float4*)(axs + (size_t)i * 32 + q * 4);
        a[q * 4] = v.x; a[q * 4 + 1] = v.y; a[q * 4 + 2] = v.z; a[q * 4 + 3] = v.w;
    }
    float acc[40];
    #pragma unroll
    for (int c = 0; c < 40; ++c) acc[c] = b[c];
    #pragma unroll
    for (int k = 0; k < 32; ++k) {
        float av = a[k];
        #pragma unroll
        for (int c = 0; c < 40; ++c) acc[c] += av * w[k * 40 + c];
    }
    float m = acc[0];
    #pragma unroll
    for (int c = 1; c < 40; ++c) m = fmaxf(m, acc[c]);
    float sum = 0.f;
    #pragma unroll
    for (int c = 0; c < 40; ++c) sum += expf(acc[c] - m);
    float lg = m + logf(sum);
    #pragma unroll
    for (int c = 0; c < 40; ++c) out[(size_t)i * 40 + c] = acc[c] - lg;
}

// ---------------- launch ----------------

extern "C" void kernel_launch(void* const* d_in, const int* in_sizes, int n_in,
                              void* d_out, int out_size, void* d_ws, size_t ws_size,
                              hipStream_t stream) {
    const float* x   = (const float*)d_in[0];
    const int*   ei  = (const int*)d_in[1];
    const float* W1a = (const float*)d_in[2];  const float* b1a = (const float*)d_in[3];
    const float* W1b = (const float*)d_in[4];  const float* b1b = (const float*)d_in[5];
    const float* W2a = (const float*)d_in[6];  const float* b2a = (const float*)d_in[7];
    const float* W2b = (const float*)d_in[8];  const float* b2b = (const float*)d_in[9];
    const float* W3a = (const float*)d_in[10]; const float* b3a = (const float*)d_in[11];
    const float* W3b = (const float*)d_in[12]; const float* b3b = (const float*)d_in[13];

    int N = in_sizes[0] / 512;
    int E = in_sizes[1] / 2;
    const int* srcv = ei;
    const int* dstv = ei + E;
    int W = (N + NB - 1) / NB;            // bucket width (<= 512 required; 391 here)
    float recipW = 1.0f / (float)W;

    char* ws = (char*)d_ws;
    size_t off = 0;
    auto alloc = [&](size_t bytes) { void* p = ws + off; off = (off + bytes + 255) & ~(size_t)255; return p; };
    int*    offs     = (int*)   alloc((size_t)(N + 1) * 4);
    float*  dinv     = (float*) alloc((size_t)N * 4);
    int*    bcntpart = (int*)   alloc((size_t)CNTB * NB * 4);
    int*    bbase    = (int*)   alloc((NB + 1) * 4);
    int*    cursor256= (int*)   alloc(NB * 4);
    int*    csr      = (int*)   alloc((size_t)E * 4);
    ushort* Wt       = (ushort*)alloc(128 * 512 * 2);
    float*  bcat     = (float*) alloc(128 * 4);
    float*  W3s      = (float*) alloc(1280 * 4);
    float*  b3s      = (float*) alloc(40 * 4);
    ushort* HWp      = (ushort*)alloc((size_t)N * 128 * 2);   // [N][128] bf16
    ushort* xsp      = (ushort*)alloc((size_t)N * 32 * 2);    // [N][32] bf16
    float*  axs      = (float*) alloc((size_t)N * 32 * 4);

    // packed edge array aliases HWp (dead until gemm; E*4 <= N*128*2)
    int* epk = (int*)HWp;

    bucketcnt_kernel<<<CNTB, 256, 0, stream>>>(dstv, bcntpart, E, W, recipW);
    scan256_kernel<<<1, 256, 0, stream>>>(bcntpart, bbase, cursor256);
    bucket_kernel<<<(E + BKE - 1) / BKE, 256, 0, stream>>>(srcv, dstv, cursor256, epk, E, W, recipW);
    sortcsr_kernel<<<NB, 256, 0, stream>>>(epk, bbase, csr, offs, dinv, N, W, E);
    prep_kernel<<<256, 256, 0, stream>>>(W1a, W1b, W2a, W2b, b1a, b1b, b2a, b2b,
                                         W3a, W3b, b3a, b3b, Wt, bcat, W3s, b3s);
    gemm_mfma<<<(N + GBM - 1) / GBM, 256, 0, stream>>>(x, Wt, dinv, HWp, N);
    agg128<<<((size_t)N * 32 + 255) / 256, 256, 0, stream>>>(HWp, dinv, offs, csr, bcat, xsp, N);
    agg32<<<((size_t)N * 4 + 255) / 256, 256, 0, stream>>>(xsp, dinv, offs, csr, axs, N);
    final_kernel<<<(N + 255) / 256, 256, 0, stream>>>(axs, W3s, b3s, (float*)d_out, N);
}